// Round 8
// baseline (683.773 us; speedup 1.0000x reference)
//
#include <hip/hip_runtime.h>
#include <hip/hip_bf16.h>

// ---------------------------------------------------------------------------
// SGCN: 3 x [GEMM -> normalized SpMM (+self loop) -> bias+ReLU] -> mean pool
//       -> linear classifier.
// CSR (dst-sorted, precomputed int2{src,coef}) built once, reused 3 layers.
// R3: LDS-aggregated build (global atomics are memory-side RMWs on gfx950).
// R5: gemm thread=node, acc[64] in VGPRs, W broadcast from LDS.
// R6: spmm lane=(edge-slot,channel-quad), 4 rows per gather instr. Result:
//     flat vs R5 -> spmm is traffic/line-rate bound, not issue bound.
// R7: (a) padded-bucket build (CAP=1280=mean+8sigma): scatterD reserves
//     directly into b*CAP+cursor; histA+exscan deleted. rowbeg/rowend arrays.
//     (b) A/B test: layer2 uses spmm4h (channel-half split, 2 passes,
//     12.8MB gather footprint each) vs layer1's spmm4 -> disambiguates
//     L2-miss-traffic-bound vs line-request-bound next round.
// ---------------------------------------------------------------------------

#define WS_ALIGN(x) (((x) + 255) & ~(size_t)255)
#define POOL_CHUNK 128
#define ECHUNK 8192                    // edges per build block
#define BSHIFT 5                       // 32 dst nodes per bucket
#define BMASK  ((1 << BSHIFT) - 1)
#define SRCBITS 17                     // N=100000 < 2^17
#define BCAP 1280                      // bucket capacity (mean 1024 + 8 sigma)

// ---- build 1: scatter edges into padded bucket regions --------------------
// LDS histogram -> one reserve atomic per (block,bucket) -> LDS-cursor
// scatter of {src|dlocal, ea} into  sbuf[b*BCAP + ...].
__global__ __launch_bounds__(256)
void scatterD_kernel(const int* __restrict__ src, const int* __restrict__ dst,
                     const float* __restrict__ ea, int E, int NB,
                     int* __restrict__ bcursor, int2* __restrict__ sbuf) {
    extern __shared__ int sh[];
    for (int i = threadIdx.x; i < NB; i += 256) sh[i] = 0;
    __syncthreads();
    int beg = blockIdx.x * ECHUNK, end = min(beg + ECHUNK, E);
    for (int i = beg + threadIdx.x; i < end; i += 256)
        atomicAdd(&sh[dst[i] >> BSHIFT], 1);
    __syncthreads();
    // one reserve atomic per (block, nonempty bucket) -> padded base position
    for (int i = threadIdx.x; i < NB; i += 256) {
        int c = sh[i];
        sh[i] = c ? (i * BCAP + atomicAdd(&bcursor[i], c)) : 0;
    }
    __syncthreads();
    for (int i = beg + threadIdx.x; i < end; i += 256) {
        int s = src[i], d = dst[i];
        int pos = atomicAdd(&sh[d >> BSHIFT], 1);        // LDS cursor
        sbuf[pos] = make_int2(s | ((d & BMASK) << SRCBITS),
                              __float_as_int(ea[i]));
    }
}

// ---- build 2: per-bucket degree count -> dinv, rowbeg/rowend --------------
__global__ __launch_bounds__(256)
void bucketE1_kernel(const int2* __restrict__ sbuf, const int* __restrict__ bcnt,
                     int N, float* __restrict__ dinv,
                     int* __restrict__ rowbeg, int* __restrict__ rowend) {
    __shared__ int dcount[32];
    if (threadIdx.x < 32) dcount[threadIdx.x] = 0;
    __syncthreads();
    int b = blockIdx.x;
    int base = b * BCAP, cnt = bcnt[b];
    for (int j = threadIdx.x; j < cnt; j += 256)
        atomicAdd(&dcount[(sbuf[base + j].x >> SRCBITS) & BMASK], 1);
    __syncthreads();
    if (threadIdx.x < 32) {
        int c = dcount[threadIdx.x];
        int x = c;
        #pragma unroll
        for (int off = 1; off < 32; off <<= 1) {
            int t = __shfl_up(x, off);
            if (threadIdx.x >= off) x += t;
        }
        int d = (b << BSHIFT) + threadIdx.x;
        if (d < N) {
            int rb = base + x - c;                       // exclusive prefix
            rowbeg[d] = rb;
            rowend[d] = rb + c;
            dinv[d]   = 1.0f / sqrtf((float)(c + 1));    // +1 = self loop
        }
    }
}

// ---- build 3: within-bucket scatter to final CSR + coefficient ------------
__global__ __launch_bounds__(256)
void bucketE2_kernel(const int2* __restrict__ sbuf, const int* __restrict__ bcnt,
                     const float* __restrict__ dinv, int N,
                     const int* __restrict__ rowbeg, int2* __restrict__ cpair) {
    __shared__ int cur[32];
    __shared__ float sdinv[32];
    int b = blockIdx.x;
    int dbase = b << BSHIFT;
    if (threadIdx.x < 32) {
        int d = dbase + threadIdx.x;
        cur[threadIdx.x]   = (d < N) ? rowbeg[d] : 0;
        sdinv[threadIdx.x] = (d < N) ? dinv[d] : 0.f;
    }
    __syncthreads();
    int base = b * BCAP, cnt = bcnt[b];
    for (int j = threadIdx.x; j < cnt; j += 256) {
        int2 e = sbuf[base + j];
        int dl = (e.x >> SRCBITS) & BMASK;
        int s  = e.x & ((1 << SRCBITS) - 1);
        float c = dinv[s] * sdinv[dl] * expf(-__int_as_float(e.y));
        int pos = atomicAdd(&cur[dl], 1);                // LDS cursor
        cpair[pos] = make_int2(s, __float_as_int(c));
    }
}

// ---- dense GEMM: Y[N,64] = X[N,K] @ W[K,64] --------------------------------
// thread = node; acc[64] static in VGPRs; W broadcast from LDS (b128).
template <int K>
__global__ __launch_bounds__(256)
void gemm3_kernel(const float* __restrict__ X, const float* __restrict__ W,
                  float* __restrict__ Y, int N) {
    __shared__ float sW[K * 64];
    for (int i = threadIdx.x; i < K * 64; i += 256) sW[i] = W[i];
    __syncthreads();
    int node = blockIdx.x * 256 + threadIdx.x;
    if (node >= N) return;
    const float4* xr = reinterpret_cast<const float4*>(X + (size_t)node * K);
    float acc[64];
    #pragma unroll
    for (int c = 0; c < 64; ++c) acc[c] = 0.f;
    #pragma unroll 2
    for (int k4 = 0; k4 < K / 4; ++k4) {
        float4 xv = xr[k4];
        #pragma unroll
        for (int j = 0; j < 4; ++j) {
            float xs = (j == 0) ? xv.x : (j == 1) ? xv.y : (j == 2) ? xv.z : xv.w;
            const float4* wr =
                reinterpret_cast<const float4*>(sW + (k4 * 4 + j) * 64);
            #pragma unroll
            for (int c4 = 0; c4 < 16; ++c4) {
                float4 wv = wr[c4];
                acc[4 * c4 + 0] = fmaf(xs, wv.x, acc[4 * c4 + 0]);
                acc[4 * c4 + 1] = fmaf(xs, wv.y, acc[4 * c4 + 1]);
                acc[4 * c4 + 2] = fmaf(xs, wv.z, acc[4 * c4 + 2]);
                acc[4 * c4 + 3] = fmaf(xs, wv.w, acc[4 * c4 + 3]);
            }
        }
    }
    float4* yr = reinterpret_cast<float4*>(Y + (size_t)node * 64);
    #pragma unroll
    for (int c4 = 0; c4 < 16; ++c4)
        yr[c4] = make_float4(acc[4 * c4 + 0], acc[4 * c4 + 1],
                             acc[4 * c4 + 2], acc[4 * c4 + 3]);
}

// ---- SpMM common: one edge's contribution to a float4 of channels ---------
__device__ __forceinline__ void quad_acc(const int2* __restrict__ cpair,
                                         int eidx, const float* __restrict__ HW,
                                         int chb, float4& acc, bool ok) {
    long long pv = __builtin_nontemporal_load(
        reinterpret_cast<const long long*>(cpair) + eidx);
    int   s = (int)(pv & 0xffffffffLL);
    float c = __int_as_float((int)(pv >> 32));
    c = ok ? c : 0.f;
    const float4 hv = *reinterpret_cast<const float4*>(
        HW + (size_t)s * 64 + chb);
    acc.x = fmaf(c, hv.x, acc.x);
    acc.y = fmaf(c, hv.y, acc.y);
    acc.z = fmaf(c, hv.z, acc.z);
    acc.w = fmaf(c, hv.w, acc.w);
}

// ---- SpMM v4: lane = (edge-slot 0..3, channel-quad 0..15), full rows ------
__global__ __launch_bounds__(256)
void spmm4_kernel(const float* __restrict__ HW,
                  const int* __restrict__ rowbeg,
                  const int* __restrict__ rowend,
                  const int2* __restrict__ cpair,
                  const float* __restrict__ dinv,
                  const float* __restrict__ bias,
                  float* __restrict__ OUT, int N) {
    int node = blockIdx.x * 4 + (threadIdx.x >> 6);
    if (node >= N) return;
    int lane = threadIdx.x & 63;
    int g    = lane >> 4;              // edge slot
    int chb  = (lane & 15) * 4;        // channel base (float4)
    int beg = rowbeg[node], end = rowend[node];
    float di = dinv[node];

    float4 a0 = make_float4(0.f, 0.f, 0.f, 0.f);
    float4 a1 = make_float4(0.f, 0.f, 0.f, 0.f);
    float4 hs = *reinterpret_cast<const float4*>(HW + (size_t)node * 64 + chb);
    if (g == 0) {
        float s2 = di * di;
        a0 = make_float4(s2 * hs.x, s2 * hs.y, s2 * hs.z, s2 * hs.w);
    }

    int j = beg;
    for (; j + 8 <= end; j += 8) {
        quad_acc(cpair, j + g,     HW, chb, a0, true);
        quad_acc(cpair, j + 4 + g, HW, chb, a1, true);
    }
    for (; j < end; j += 4) {
        int e = j + g;
        bool ok = e < end;
        quad_acc(cpair, ok ? e : beg, HW, chb, a0, ok);
    }

    float4 r = make_float4(a0.x + a1.x, a0.y + a1.y, a0.z + a1.z, a0.w + a1.w);
    r.x += __shfl_xor(r.x, 32); r.y += __shfl_xor(r.y, 32);
    r.z += __shfl_xor(r.z, 32); r.w += __shfl_xor(r.w, 32);
    r.x += __shfl_xor(r.x, 16); r.y += __shfl_xor(r.y, 16);
    r.z += __shfl_xor(r.z, 16); r.w += __shfl_xor(r.w, 16);

    if (lane < 16) {
        float4 bv = *reinterpret_cast<const float4*>(bias + chb);
        float4 o;
        o.x = fmaxf(r.x + bv.x, 0.f);
        o.y = fmaxf(r.y + bv.y, 0.f);
        o.z = fmaxf(r.z + bv.z, 0.f);
        o.w = fmaxf(r.w + bv.w, 0.f);
        *reinterpret_cast<float4*>(OUT + (size_t)node * 64 + chb) = o;
    }
}

// ---- SpMM v4h: channel-half pass (A/B probe). lane=(slot 0..7, quad 0..7) -
// Gather footprint per pass = 12.8MB (half rows); launched twice (half=0,1).
__global__ __launch_bounds__(256)
void spmm4h_kernel(const float* __restrict__ HW,
                   const int* __restrict__ rowbeg,
                   const int* __restrict__ rowend,
                   const int2* __restrict__ cpair,
                   const float* __restrict__ dinv,
                   const float* __restrict__ bias,
                   float* __restrict__ OUT, int N, int half) {
    int node = blockIdx.x * 4 + (threadIdx.x >> 6);
    if (node >= N) return;
    int lane = threadIdx.x & 63;
    int g    = lane >> 3;                      // edge slot 0..7
    int chb  = (lane & 7) * 4 + half * 32;     // channel base (float4)
    int beg = rowbeg[node], end = rowend[node];
    float di = dinv[node];

    float4 a0 = make_float4(0.f, 0.f, 0.f, 0.f);
    float4 hs = *reinterpret_cast<const float4*>(HW + (size_t)node * 64 + chb);
    if (g == 0) {
        float s2 = di * di;
        a0 = make_float4(s2 * hs.x, s2 * hs.y, s2 * hs.z, s2 * hs.w);
    }

    int j = beg;
    for (; j + 8 <= end; j += 8)
        quad_acc(cpair, j + g, HW, chb, a0, true);
    if (j < end) {
        int e = j + g;
        bool ok = e < end;
        quad_acc(cpair, ok ? e : beg, HW, chb, a0, ok);
    }

    a0.x += __shfl_xor(a0.x, 32); a0.y += __shfl_xor(a0.y, 32);
    a0.z += __shfl_xor(a0.z, 32); a0.w += __shfl_xor(a0.w, 32);
    a0.x += __shfl_xor(a0.x, 16); a0.y += __shfl_xor(a0.y, 16);
    a0.z += __shfl_xor(a0.z, 16); a0.w += __shfl_xor(a0.w, 16);
    a0.x += __shfl_xor(a0.x, 8);  a0.y += __shfl_xor(a0.y, 8);
    a0.z += __shfl_xor(a0.z, 8);  a0.w += __shfl_xor(a0.w, 8);

    if (lane < 8) {
        float4 bv = *reinterpret_cast<const float4*>(bias + chb);
        float4 o;
        o.x = fmaxf(a0.x + bv.x, 0.f);
        o.y = fmaxf(a0.y + bv.y, 0.f);
        o.z = fmaxf(a0.z + bv.z, 0.f);
        o.w = fmaxf(a0.w + bv.w, 0.f);
        *reinterpret_cast<float4*>(OUT + (size_t)node * 64 + chb) = o;
    }
}

// ---- pool stage 1: per-chunk per-graph partial sums -----------------------
__global__ __launch_bounds__(256)
void pool1_kernel(const float* __restrict__ H, const int* __restrict__ batch,
                  int N, int B, float* __restrict__ partial) {
    __shared__ float part[4][16][64];
    int lane = threadIdx.x & 63, wid = threadIdx.x >> 6;
    for (int g = 0; g < 16; ++g) part[wid][g][lane] = 0.f;
    int beg = blockIdx.x * POOL_CHUNK;
    int end = min(beg + POOL_CHUNK, N);
    float acc = 0.f; int cur = -1;
    for (int v = beg + wid; v < end; v += 4) {
        int g = batch[v];
        if (g != cur) {
            if (cur >= 0) part[wid][cur][lane] += acc;
            cur = g; acc = 0.f;
        }
        acc += H[(size_t)v * 64 + lane];
    }
    if (cur >= 0) part[wid][cur][lane] += acc;
    __syncthreads();
    float* outp = partial + (size_t)blockIdx.x * B * 64;
    for (int idx = threadIdx.x; idx < B * 64; idx += 256) {
        int g = idx >> 6, l = idx & 63;
        outp[idx] = part[0][g][l] + part[1][g][l] + part[2][g][l] + part[3][g][l];
    }
}

// ---- pool stage 2: fixed-order reduce over blocks, divide by count --------
__global__ __launch_bounds__(256)
void pool2_kernel(const float* __restrict__ partial, int nblk, int B,
                  const int* __restrict__ batch, int N,
                  float* __restrict__ pooled) {
    int g = blockIdx.x;
    int lane = threadIdx.x & 63, wid = threadIdx.x >> 6;
    float acc = 0.f;
    for (int b = wid; b < nblk; b += 4)
        acc += partial[(size_t)b * B * 64 + g * 64 + lane];
    __shared__ float sacc[4][64];
    sacc[wid][lane] = acc;
    __syncthreads();
    if (wid == 0) {
        int lo = 0, hi = N;
        while (lo < hi) { int m = (lo + hi) >> 1; if (batch[m] < g) lo = m + 1; else hi = m; }
        int s0 = lo;
        lo = 0; hi = N;
        while (lo < hi) { int m = (lo + hi) >> 1; if (batch[m] < g + 1) lo = m + 1; else hi = m; }
        float cnt = (float)(lo - s0);
        float s = sacc[0][lane] + sacc[1][lane] + sacc[2][lane] + sacc[3][lane];
        pooled[g * 64 + lane] = s / fmaxf(cnt, 1.0f);
    }
}

// ---- classifier: out[B,C] = pooled[B,64] @ Wc[64,C] + bc ------------------
__global__ __launch_bounds__(256)
void final_kernel(const float* __restrict__ pooled, const float* __restrict__ Wc,
                  const float* __restrict__ bc, float* __restrict__ out, int C) {
    int b = blockIdx.x;
    __shared__ float sp[64];
    if (threadIdx.x < 64) sp[threadIdx.x] = pooled[b * 64 + threadIdx.x];
    __syncthreads();
    for (int c = threadIdx.x; c < C; c += blockDim.x) {
        float acc = bc[c];
        #pragma unroll
        for (int k = 0; k < 64; ++k) acc = fmaf(sp[k], Wc[k * C + c], acc);
        out[b * C + c] = acc;
    }
}

extern "C" void kernel_launch(void* const* d_in, const int* in_sizes, int n_in,
                              void* d_out, int out_size, void* d_ws, size_t ws_size,
                              hipStream_t stream) {
    const float* x     = (const float*)d_in[0];
    const int*   esrc  = (const int*)  d_in[1];
    const int*   edst  = (const int*)  d_in[2];
    const float* ea    = (const float*)d_in[3];
    const int*   batch = (const int*)  d_in[4];
    const float* W0 = (const float*)d_in[5];  const float* b0 = (const float*)d_in[6];
    const float* W1 = (const float*)d_in[7];  const float* b1 = (const float*)d_in[8];
    const float* W2 = (const float*)d_in[9];  const float* b2 = (const float*)d_in[10];
    const float* Wc = (const float*)d_in[11]; const float* bc = (const float*)d_in[12];

    const int N = in_sizes[4];
    const int E = in_sizes[1];
    const int C = in_sizes[12];            // 196
    const int B = out_size / C;            // 16
    (void)n_in; (void)ws_size;

    const int NB        = (N + BMASK) >> BSHIFT;              // dst buckets
    const int nchunk    = (E + ECHUNK - 1) / ECHUNK;          // build chunks
    const int nblk_pool = (N + POOL_CHUNK - 1) / POOL_CHUNK;
    const size_t PADDED = (size_t)NB * BCAP;                  // padded entries

    // ---- carve workspace ----
    char* w = (char*)d_ws;
    auto alloc = [&](size_t bytes) { void* p = (void*)w; w += WS_ALIGN(bytes); return p; };
    float* d_dinv    = (float*)alloc((size_t)N * 4);
    int*   d_rowbeg  = (int*)  alloc((size_t)N * 4);
    int*   d_rowend  = (int*)  alloc((size_t)N * 4);
    int*   d_bcursor = (int*)  alloc((size_t)NB * 4);
    int2*  d_cpair   = (int2*) alloc(PADDED * 8);
    float* d_hA      = (float*)alloc((size_t)N * 64 * 4);
    size_t tmp_bytes = (size_t)N * 64 * 4;
    if (PADDED * 8 > tmp_bytes) tmp_bytes = PADDED * 8;
    float* d_tmp     = (float*)alloc(tmp_bytes);
    float* d_partial = (float*)alloc((size_t)nblk_pool * B * 64 * 4);
    float* d_pool    = (float*)alloc((size_t)B * 64 * 4);
    int2*  d_sbuf    = (int2*)d_tmp;   // alias: staging dead before first gemm

    // ---- build CSR (padded buckets; no global histogram / scan) ----
    hipMemsetAsync(d_bcursor, 0, (size_t)NB * 4, stream);
    scatterD_kernel<<<nchunk, 256, NB * 4, stream>>>(esrc, edst, ea, E, NB,
                                                     d_bcursor, d_sbuf);
    bucketE1_kernel<<<NB, 256, 0, stream>>>(d_sbuf, d_bcursor, N, d_dinv,
                                            d_rowbeg, d_rowend);
    bucketE2_kernel<<<NB, 256, 0, stream>>>(d_sbuf, d_bcursor, d_dinv, N,
                                            d_rowbeg, d_cpair);

    const int nblk = (N + 3) / 4;
    const int gblk = (N + 255) / 256;
    // ---- layer 0 (K=128) ----
    gemm3_kernel<128><<<gblk, 256, 0, stream>>>(x, W0, d_tmp, N);
    spmm4_kernel<<<nblk, 256, 0, stream>>>(d_tmp, d_rowbeg, d_rowend, d_cpair,
                                           d_dinv, b0, d_hA, N);
    // ---- layer 1 (K=64) ----
    gemm3_kernel<64><<<gblk, 256, 0, stream>>>(d_hA, W1, d_tmp, N);
    spmm4_kernel<<<nblk, 256, 0, stream>>>(d_tmp, d_rowbeg, d_rowend, d_cpair,
                                           d_dinv, b1, d_hA, N);
    // ---- layer 2 (K=64): A/B probe -- channel-half split, 2 passes ----
    gemm3_kernel<64><<<gblk, 256, 0, stream>>>(d_hA, W2, d_tmp, N);
    spmm4h_kernel<<<nblk, 256, 0, stream>>>(d_tmp, d_rowbeg, d_rowend, d_cpair,
                                            d_dinv, b2, d_hA, N, 0);
    spmm4h_kernel<<<nblk, 256, 0, stream>>>(d_tmp, d_rowbeg, d_rowend, d_cpair,
                                            d_dinv, b2, d_hA, N, 1);

    // ---- pool + classifier ----
    pool1_kernel<<<nblk_pool, 256, 0, stream>>>(d_hA, batch, N, B, d_partial);
    pool2_kernel<<<B, 256, 0, stream>>>(d_partial, nblk_pool, B, batch, N, d_pool);
    final_kernel<<<B, 256, 0, stream>>>(d_pool, Wc, bc, (float*)d_out, C);
}

// Round 10
// 646.661 us; speedup vs baseline: 1.0574x; 1.0574x over previous
//
#include <hip/hip_runtime.h>
#include <hip/hip_bf16.h>

// ---------------------------------------------------------------------------
// SGCN: 3 x [GEMM -> normalized SpMM (+self loop) -> bias+ReLU] -> mean pool
//       -> linear classifier.
// CSR (dst-sorted, precomputed int2{src,coef}) built once, reused 3 layers.
// R3: LDS-aggregated build (global atomics are memory-side RMWs on gfx950).
// R5: gemm thread=node, acc[64] in VGPRs, W broadcast from LDS.
// R6/R7: spmm is L2-miss line-traffic bound (dur == FETCH/3.7TB/s across all
//     variants; channel-half A/B pair was slower). Keep spmm4 full-row.
// R7: padded-bucket build (BCAP=1280), histA/exscan deleted.
// R8: (a) layer2 back to spmm4; (b) OUT stored nontemporally; (c) scatterD
//     512 threads/block.
// R9: fix NT-store compile error (HIP float4 is a class; use clang
//     ext_vector_type(4) alias for __builtin_nontemporal_store).
// ---------------------------------------------------------------------------

#define WS_ALIGN(x) (((x) + 255) & ~(size_t)255)
#define POOL_CHUNK 128
#define ECHUNK 8192                    // edges per build block
#define BSHIFT 5                       // 32 dst nodes per bucket
#define BMASK  ((1 << BSHIFT) - 1)
#define SRCBITS 17                     // N=100000 < 2^17
#define BCAP 1280                      // bucket capacity (mean 1024 + 8 sigma)

typedef float f32x4 __attribute__((ext_vector_type(4)));

// ---- build 1: scatter edges into padded bucket regions --------------------
__global__ __launch_bounds__(512)
void scatterD_kernel(const int* __restrict__ src, const int* __restrict__ dst,
                     const float* __restrict__ ea, int E, int NB,
                     int* __restrict__ bcursor, int2* __restrict__ sbuf) {
    extern __shared__ int sh[];
    for (int i = threadIdx.x; i < NB; i += 512) sh[i] = 0;
    __syncthreads();
    int beg = blockIdx.x * ECHUNK, end = min(beg + ECHUNK, E);
    for (int i = beg + threadIdx.x; i < end; i += 512)
        atomicAdd(&sh[dst[i] >> BSHIFT], 1);
    __syncthreads();
    // one reserve atomic per (block, nonempty bucket) -> padded base position
    for (int i = threadIdx.x; i < NB; i += 512) {
        int c = sh[i];
        sh[i] = c ? (i * BCAP + atomicAdd(&bcursor[i], c)) : 0;
    }
    __syncthreads();
    for (int i = beg + threadIdx.x; i < end; i += 512) {
        int s = src[i], d = dst[i];
        int pos = atomicAdd(&sh[d >> BSHIFT], 1);        // LDS cursor
        sbuf[pos] = make_int2(s | ((d & BMASK) << SRCBITS),
                              __float_as_int(ea[i]));
    }
}

// ---- build 2: per-bucket degree count -> dinv, rowbeg/rowend --------------
__global__ __launch_bounds__(256)
void bucketE1_kernel(const int2* __restrict__ sbuf, const int* __restrict__ bcnt,
                     int N, float* __restrict__ dinv,
                     int* __restrict__ rowbeg, int* __restrict__ rowend) {
    __shared__ int dcount[32];
    if (threadIdx.x < 32) dcount[threadIdx.x] = 0;
    __syncthreads();
    int b = blockIdx.x;
    int base = b * BCAP, cnt = bcnt[b];
    for (int j = threadIdx.x; j < cnt; j += 256)
        atomicAdd(&dcount[(sbuf[base + j].x >> SRCBITS) & BMASK], 1);
    __syncthreads();
    if (threadIdx.x < 32) {
        int c = dcount[threadIdx.x];
        int x = c;
        #pragma unroll
        for (int off = 1; off < 32; off <<= 1) {
            int t = __shfl_up(x, off);
            if (threadIdx.x >= off) x += t;
        }
        int d = (b << BSHIFT) + threadIdx.x;
        if (d < N) {
            int rb = base + x - c;                       // exclusive prefix
            rowbeg[d] = rb;
            rowend[d] = rb + c;
            dinv[d]   = 1.0f / sqrtf((float)(c + 1));    // +1 = self loop
        }
    }
}

// ---- build 3: within-bucket scatter to final CSR + coefficient ------------
__global__ __launch_bounds__(256)
void bucketE2_kernel(const int2* __restrict__ sbuf, const int* __restrict__ bcnt,
                     const float* __restrict__ dinv, int N,
                     const int* __restrict__ rowbeg, int2* __restrict__ cpair) {
    __shared__ int cur[32];
    __shared__ float sdinv[32];
    int b = blockIdx.x;
    int dbase = b << BSHIFT;
    if (threadIdx.x < 32) {
        int d = dbase + threadIdx.x;
        cur[threadIdx.x]   = (d < N) ? rowbeg[d] : 0;
        sdinv[threadIdx.x] = (d < N) ? dinv[d] : 0.f;
    }
    __syncthreads();
    int base = b * BCAP, cnt = bcnt[b];
    for (int j = threadIdx.x; j < cnt; j += 256) {
        int2 e = sbuf[base + j];
        int dl = (e.x >> SRCBITS) & BMASK;
        int s  = e.x & ((1 << SRCBITS) - 1);
        float c = dinv[s] * sdinv[dl] * expf(-__int_as_float(e.y));
        int pos = atomicAdd(&cur[dl], 1);                // LDS cursor
        cpair[pos] = make_int2(s, __float_as_int(c));
    }
}

// ---- dense GEMM: Y[N,64] = X[N,K] @ W[K,64] --------------------------------
// thread = node; acc[64] static in VGPRs; W broadcast from LDS (b128).
template <int K>
__global__ __launch_bounds__(256)
void gemm3_kernel(const float* __restrict__ X, const float* __restrict__ W,
                  float* __restrict__ Y, int N) {
    __shared__ float sW[K * 64];
    for (int i = threadIdx.x; i < K * 64; i += 256) sW[i] = W[i];
    __syncthreads();
    int node = blockIdx.x * 256 + threadIdx.x;
    if (node >= N) return;
    const float4* xr = reinterpret_cast<const float4*>(X + (size_t)node * K);
    float acc[64];
    #pragma unroll
    for (int c = 0; c < 64; ++c) acc[c] = 0.f;
    #pragma unroll 2
    for (int k4 = 0; k4 < K / 4; ++k4) {
        float4 xv = xr[k4];
        #pragma unroll
        for (int j = 0; j < 4; ++j) {
            float xs = (j == 0) ? xv.x : (j == 1) ? xv.y : (j == 2) ? xv.z : xv.w;
            const float4* wr =
                reinterpret_cast<const float4*>(sW + (k4 * 4 + j) * 64);
            #pragma unroll
            for (int c4 = 0; c4 < 16; ++c4) {
                float4 wv = wr[c4];
                acc[4 * c4 + 0] = fmaf(xs, wv.x, acc[4 * c4 + 0]);
                acc[4 * c4 + 1] = fmaf(xs, wv.y, acc[4 * c4 + 1]);
                acc[4 * c4 + 2] = fmaf(xs, wv.z, acc[4 * c4 + 2]);
                acc[4 * c4 + 3] = fmaf(xs, wv.w, acc[4 * c4 + 3]);
            }
        }
    }
    float4* yr = reinterpret_cast<float4*>(Y + (size_t)node * 64);
    #pragma unroll
    for (int c4 = 0; c4 < 16; ++c4)
        yr[c4] = make_float4(acc[4 * c4 + 0], acc[4 * c4 + 1],
                             acc[4 * c4 + 2], acc[4 * c4 + 3]);
}

// ---- SpMM common: one edge's contribution to a float4 of channels ---------
__device__ __forceinline__ void quad_acc(const int2* __restrict__ cpair,
                                         int eidx, const float* __restrict__ HW,
                                         int chb, float4& acc, bool ok) {
    long long pv = __builtin_nontemporal_load(
        reinterpret_cast<const long long*>(cpair) + eidx);
    int   s = (int)(pv & 0xffffffffLL);
    float c = __int_as_float((int)(pv >> 32));
    c = ok ? c : 0.f;
    const float4 hv = *reinterpret_cast<const float4*>(
        HW + (size_t)s * 64 + chb);
    acc.x = fmaf(c, hv.x, acc.x);
    acc.y = fmaf(c, hv.y, acc.y);
    acc.z = fmaf(c, hv.z, acc.z);
    acc.w = fmaf(c, hv.w, acc.w);
}

// ---- SpMM v4: lane = (edge-slot 0..3, channel-quad 0..15), full rows ------
// OUT written nontemporally (never re-read here; keep L2 for the gather set).
__global__ __launch_bounds__(256)
void spmm4_kernel(const float* __restrict__ HW,
                  const int* __restrict__ rowbeg,
                  const int* __restrict__ rowend,
                  const int2* __restrict__ cpair,
                  const float* __restrict__ dinv,
                  const float* __restrict__ bias,
                  float* __restrict__ OUT, int N) {
    int node = blockIdx.x * 4 + (threadIdx.x >> 6);
    if (node >= N) return;
    int lane = threadIdx.x & 63;
    int g    = lane >> 4;              // edge slot
    int chb  = (lane & 15) * 4;        // channel base (float4)
    int beg = rowbeg[node], end = rowend[node];
    float di = dinv[node];

    float4 a0 = make_float4(0.f, 0.f, 0.f, 0.f);
    float4 a1 = make_float4(0.f, 0.f, 0.f, 0.f);
    float4 hs = *reinterpret_cast<const float4*>(HW + (size_t)node * 64 + chb);
    if (g == 0) {
        float s2 = di * di;
        a0 = make_float4(s2 * hs.x, s2 * hs.y, s2 * hs.z, s2 * hs.w);
    }

    int j = beg;
    for (; j + 8 <= end; j += 8) {
        quad_acc(cpair, j + g,     HW, chb, a0, true);
        quad_acc(cpair, j + 4 + g, HW, chb, a1, true);
    }
    for (; j < end; j += 4) {
        int e = j + g;
        bool ok = e < end;
        quad_acc(cpair, ok ? e : beg, HW, chb, a0, ok);
    }

    float4 r = make_float4(a0.x + a1.x, a0.y + a1.y, a0.z + a1.z, a0.w + a1.w);
    r.x += __shfl_xor(r.x, 32); r.y += __shfl_xor(r.y, 32);
    r.z += __shfl_xor(r.z, 32); r.w += __shfl_xor(r.w, 32);
    r.x += __shfl_xor(r.x, 16); r.y += __shfl_xor(r.y, 16);
    r.z += __shfl_xor(r.z, 16); r.w += __shfl_xor(r.w, 16);

    if (lane < 16) {
        float4 bv = *reinterpret_cast<const float4*>(bias + chb);
        f32x4 o;
        o.x = fmaxf(r.x + bv.x, 0.f);
        o.y = fmaxf(r.y + bv.y, 0.f);
        o.z = fmaxf(r.z + bv.z, 0.f);
        o.w = fmaxf(r.w + bv.w, 0.f);
        __builtin_nontemporal_store(o, reinterpret_cast<f32x4*>(
            OUT + (size_t)node * 64 + chb));
    }
}

// ---- pool stage 1: per-chunk per-graph partial sums -----------------------
__global__ __launch_bounds__(256)
void pool1_kernel(const float* __restrict__ H, const int* __restrict__ batch,
                  int N, int B, float* __restrict__ partial) {
    __shared__ float part[4][16][64];
    int lane = threadIdx.x & 63, wid = threadIdx.x >> 6;
    for (int g = 0; g < 16; ++g) part[wid][g][lane] = 0.f;
    int beg = blockIdx.x * POOL_CHUNK;
    int end = min(beg + POOL_CHUNK, N);
    float acc = 0.f; int cur = -1;
    for (int v = beg + wid; v < end; v += 4) {
        int g = batch[v];
        if (g != cur) {
            if (cur >= 0) part[wid][cur][lane] += acc;
            cur = g; acc = 0.f;
        }
        acc += H[(size_t)v * 64 + lane];
    }
    if (cur >= 0) part[wid][cur][lane] += acc;
    __syncthreads();
    float* outp = partial + (size_t)blockIdx.x * B * 64;
    for (int idx = threadIdx.x; idx < B * 64; idx += 256) {
        int g = idx >> 6, l = idx & 63;
        outp[idx] = part[0][g][l] + part[1][g][l] + part[2][g][l] + part[3][g][l];
    }
}

// ---- pool stage 2: fixed-order reduce over blocks, divide by count --------
__global__ __launch_bounds__(256)
void pool2_kernel(const float* __restrict__ partial, int nblk, int B,
                  const int* __restrict__ batch, int N,
                  float* __restrict__ pooled) {
    int g = blockIdx.x;
    int lane = threadIdx.x & 63, wid = threadIdx.x >> 6;
    float acc = 0.f;
    for (int b = wid; b < nblk; b += 4)
        acc += partial[(size_t)b * B * 64 + g * 64 + lane];
    __shared__ float sacc[4][64];
    sacc[wid][lane] = acc;
    __syncthreads();
    if (wid == 0) {
        int lo = 0, hi = N;
        while (lo < hi) { int m = (lo + hi) >> 1; if (batch[m] < g) lo = m + 1; else hi = m; }
        int s0 = lo;
        lo = 0; hi = N;
        while (lo < hi) { int m = (lo + hi) >> 1; if (batch[m] < g + 1) lo = m + 1; else hi = m; }
        float cnt = (float)(lo - s0);
        float s = sacc[0][lane] + sacc[1][lane] + sacc[2][lane] + sacc[3][lane];
        pooled[g * 64 + lane] = s / fmaxf(cnt, 1.0f);
    }
}

// ---- classifier: out[B,C] = pooled[B,64] @ Wc[64,C] + bc ------------------
__global__ __launch_bounds__(256)
void final_kernel(const float* __restrict__ pooled, const float* __restrict__ Wc,
                  const float* __restrict__ bc, float* __restrict__ out, int C) {
    int b = blockIdx.x;
    __shared__ float sp[64];
    if (threadIdx.x < 64) sp[threadIdx.x] = pooled[b * 64 + threadIdx.x];
    __syncthreads();
    for (int c = threadIdx.x; c < C; c += blockDim.x) {
        float acc = bc[c];
        #pragma unroll
        for (int k = 0; k < 64; ++k) acc = fmaf(sp[k], Wc[k * C + c], acc);
        out[b * C + c] = acc;
    }
}

extern "C" void kernel_launch(void* const* d_in, const int* in_sizes, int n_in,
                              void* d_out, int out_size, void* d_ws, size_t ws_size,
                              hipStream_t stream) {
    const float* x     = (const float*)d_in[0];
    const int*   esrc  = (const int*)  d_in[1];
    const int*   edst  = (const int*)  d_in[2];
    const float* ea    = (const float*)d_in[3];
    const int*   batch = (const int*)  d_in[4];
    const float* W0 = (const float*)d_in[5];  const float* b0 = (const float*)d_in[6];
    const float* W1 = (const float*)d_in[7];  const float* b1 = (const float*)d_in[8];
    const float* W2 = (const float*)d_in[9];  const float* b2 = (const float*)d_in[10];
    const float* Wc = (const float*)d_in[11]; const float* bc = (const float*)d_in[12];

    const int N = in_sizes[4];
    const int E = in_sizes[1];
    const int C = in_sizes[12];            // 196
    const int B = out_size / C;            // 16
    (void)n_in; (void)ws_size;

    const int NB        = (N + BMASK) >> BSHIFT;              // dst buckets
    const int nchunk    = (E + ECHUNK - 1) / ECHUNK;          // build chunks
    const int nblk_pool = (N + POOL_CHUNK - 1) / POOL_CHUNK;
    const size_t PADDED = (size_t)NB * BCAP;                  // padded entries

    // ---- carve workspace ----
    char* w = (char*)d_ws;
    auto alloc = [&](size_t bytes) { void* p = (void*)w; w += WS_ALIGN(bytes); return p; };
    float* d_dinv    = (float*)alloc((size_t)N * 4);
    int*   d_rowbeg  = (int*)  alloc((size_t)N * 4);
    int*   d_rowend  = (int*)  alloc((size_t)N * 4);
    int*   d_bcursor = (int*)  alloc((size_t)NB * 4);
    int2*  d_cpair   = (int2*) alloc(PADDED * 8);
    float* d_hA      = (float*)alloc((size_t)N * 64 * 4);
    size_t tmp_bytes = (size_t)N * 64 * 4;
    if (PADDED * 8 > tmp_bytes) tmp_bytes = PADDED * 8;
    float* d_tmp     = (float*)alloc(tmp_bytes);
    float* d_partial = (float*)alloc((size_t)nblk_pool * B * 64 * 4);
    float* d_pool    = (float*)alloc((size_t)B * 64 * 4);
    int2*  d_sbuf    = (int2*)d_tmp;   // alias: staging dead before first gemm

    // ---- build CSR (padded buckets; no global histogram / scan) ----
    hipMemsetAsync(d_bcursor, 0, (size_t)NB * 4, stream);
    scatterD_kernel<<<nchunk, 512, NB * 4, stream>>>(esrc, edst, ea, E, NB,
                                                     d_bcursor, d_sbuf);
    bucketE1_kernel<<<NB, 256, 0, stream>>>(d_sbuf, d_bcursor, N, d_dinv,
                                            d_rowbeg, d_rowend);
    bucketE2_kernel<<<NB, 256, 0, stream>>>(d_sbuf, d_bcursor, d_dinv, N,
                                            d_rowbeg, d_cpair);

    const int nblk = (N + 3) / 4;
    const int gblk = (N + 255) / 256;
    // ---- layer 0 (K=128) ----
    gemm3_kernel<128><<<gblk, 256, 0, stream>>>(x, W0, d_tmp, N);
    spmm4_kernel<<<nblk, 256, 0, stream>>>(d_tmp, d_rowbeg, d_rowend, d_cpair,
                                           d_dinv, b0, d_hA, N);
    // ---- layer 1 (K=64) ----
    gemm3_kernel<64><<<gblk, 256, 0, stream>>>(d_hA, W1, d_tmp, N);
    spmm4_kernel<<<nblk, 256, 0, stream>>>(d_tmp, d_rowbeg, d_rowend, d_cpair,
                                           d_dinv, b1, d_hA, N);
    // ---- layer 2 (K=64) ----
    gemm3_kernel<64><<<gblk, 256, 0, stream>>>(d_hA, W2, d_tmp, N);
    spmm4_kernel<<<nblk, 256, 0, stream>>>(d_tmp, d_rowbeg, d_rowend, d_cpair,
                                           d_dinv, b2, d_hA, N);

    // ---- pool + classifier ----
    pool1_kernel<<<nblk_pool, 256, 0, stream>>>(d_hA, batch, N, B, d_partial);
    pool2_kernel<<<B, 256, 0, stream>>>(d_partial, nblk_pool, B, batch, N, d_pool);
    final_kernel<<<B, 256, 0, stream>>>(d_pool, Wc, bc, (float*)d_out, C);
}